// Round 1
// baseline (2404.493 us; speedup 1.0000x reference)
//
#include <hip/hip_runtime.h>
#include <cstdint>
#include <cstddef>

#define B_ 2
#define D_ 4096
#define S_ 2048
#define F_ 16384

typedef __attribute__((ext_vector_type(8))) short bf16x8;
typedef __attribute__((ext_vector_type(4))) float f32x4;
typedef __attribute__((ext_vector_type(4))) unsigned short u16x4;

__device__ __forceinline__ unsigned short f2bf(float f) {
  union { float f; unsigned int u; } c; c.f = f;
  unsigned int u = c.u + 0x7fffu + ((c.u >> 16) & 1u);
  return (unsigned short)(u >> 16);
}

__device__ __forceinline__ float bf2f(unsigned short u) {
  union { unsigned int i; float f; } c; c.i = ((unsigned int)u) << 16;
  return c.f;
}

// ---------------- convert fp32 -> bf16 (vectorized) ----------------
__global__ void cvt_kernel(const float4* __restrict__ src, ushort4* __restrict__ dst, int n4) {
  int i = blockIdx.x * blockDim.x + threadIdx.x;
  if (i >= n4) return;
  float4 v = src[i];
  ushort4 o;
  o.x = f2bf(v.x); o.y = f2bf(v.y); o.z = f2bf(v.z); o.w = f2bf(v.w);
  dst[i] = o;
}

// ---------------- transpose-cast x (B,D,S) f32 -> xt (B,S,D) bf16 ----------------
__global__ void transpose_cast_kernel(const float* __restrict__ x, unsigned short* __restrict__ xt) {
  __shared__ float t[32][33];
  int b = blockIdx.z;
  int d0 = blockIdx.y * 32, s0 = blockIdx.x * 32;
  const float* xb = x + (size_t)b * D_ * S_;
  unsigned short* xtb = xt + (size_t)b * S_ * D_;
  int tx = threadIdx.x;   // 0..31
  int ty = threadIdx.y;   // 0..7
#pragma unroll
  for (int r = 0; r < 4; ++r)
    t[ty + r * 8][tx] = xb[(size_t)(d0 + ty + r * 8) * S_ + s0 + tx];
  __syncthreads();
#pragma unroll
  for (int r = 0; r < 4; ++r)
    xtb[(size_t)(s0 + ty + r * 8) * D_ + d0 + tx] = f2bf(t[tx][ty + r * 8]);
}

// ---------------- 256x256 tile GEMM core (8-phase-style schedule) ----------------
// LDS per tile operand: 256 rows x 64 cols bf16 = 32 KiB, as 16B granules.
// granule (m, kbs) in LDS holds global granule (m, kbs ^ (m&7))  [XOR swizzle].
// Double-buffered A+B = 128 KiB.
__device__ __forceinline__ void stage_half(const unsigned short* g, int ld,
                                           unsigned short* lds, int tid, int half) {
#pragma unroll
  for (int c = 0; c < 2; ++c) {
    int gran = half * 1024 + c * 512 + tid;   // 0..2047 over both halves
    int m = gran >> 3;                        // row 0..255
    int kb = (gran & 7) ^ (m & 7);            // source granule within row
    const unsigned short* gp = g + (size_t)m * ld + kb * 8;
    __builtin_amdgcn_global_load_lds(
        (const __attribute__((address_space(1))) unsigned int*)gp,
        (__attribute__((address_space(3))) unsigned int*)(lds + gran * 8),
        16, 0, 0);
  }
}

__device__ __forceinline__ bf16x8 frag_load(const unsigned short* tile, int row, int kb) {
  int off = (row * 8 + (kb ^ (row & 7))) * 8;
  return *(const bf16x8*)(tile + off);
}

// 512 threads = 8 waves as 2(M)x4(N); per-wave output 128x64 = acc[8][4] f32x4.
__device__ __forceinline__ void mainloop_256(const unsigned short* __restrict__ ag,
                                             const unsigned short* __restrict__ bg,
                                             const int ld, const int nt,
                                             unsigned short* sh, const int tid,
                                             f32x4 (&acc)[8][4]) {
  unsigned short* As0 = sh;
  unsigned short* Bs0 = sh + 16384;
  unsigned short* As1 = sh + 32768;
  unsigned short* Bs1 = sh + 49152;
  const int lane = tid & 63;
  const int wid = tid >> 6;
  const int wm = (wid >> 2) * 128;
  const int wn = (wid & 3) * 64;
  const int lr = lane & 15;
  const int kq = lane >> 4;   // 0..3

  // prologue: tile 0 -> buf0 (8 load instructions)
  stage_half(ag, ld, As0, tid, 0);
  stage_half(ag, ld, As0, tid, 1);
  stage_half(bg, ld, Bs0, tid, 0);
  stage_half(bg, ld, Bs0, tid, 1);

  for (int t = 0; t < nt; ++t) {
    unsigned short* A  = (t & 1) ? As1 : As0;
    unsigned short* Bt = (t & 1) ? Bs1 : Bs0;
    unsigned short* An = (t & 1) ? As0 : As1;
    unsigned short* Bn = (t & 1) ? Bs0 : Bs1;
    const unsigned short* agn = ag + (size_t)(t + 1) * 64;
    const unsigned short* bgn = bg + (size_t)(t + 1) * 64;
    const bool pf = (t + 1 < nt);
#pragma unroll
    for (int q = 0; q < 4; ++q) {
      if (q == 0) {
        // issue next tile's A halves, then counted wait: tile t's 8 loads
        // drained, the 4 just-issued stay in flight across the barrier.
        if (pf) {
          stage_half(agn, ld, An, tid, 0);
          stage_half(agn, ld, An, tid, 1);
          asm volatile("s_waitcnt vmcnt(4)" ::: "memory");
        } else {
          asm volatile("s_waitcnt vmcnt(0)" ::: "memory");
        }
        __builtin_amdgcn_s_barrier();
      }
      const int qi = q >> 1, qj = q & 1;   // quadrant: rows qi*64, cols qj*32
      bf16x8 af[2][4], bfr[2][2];
#pragma unroll
      for (int kk = 0; kk < 2; ++kk) {
        const int kb = kk * 4 + kq;
#pragma unroll
        for (int j = 0; j < 2; ++j)
          bfr[kk][j] = frag_load(Bt, wn + qj * 32 + j * 16 + lr, kb);
#pragma unroll
        for (int i = 0; i < 4; ++i)
          af[kk][i] = frag_load(A, wm + qi * 64 + i * 16 + lr, kb);
      }
      if (pf) {
        if (q == 1) stage_half(bgn, ld, Bn, tid, 0);
        if (q == 2) stage_half(bgn, ld, Bn, tid, 1);
      }
      __builtin_amdgcn_s_barrier();
      asm volatile("s_waitcnt lgkmcnt(0)" ::: "memory");
      __builtin_amdgcn_sched_barrier(0);
      __builtin_amdgcn_s_setprio(1);
#pragma unroll
      for (int kk = 0; kk < 2; ++kk)
#pragma unroll
        for (int i = 0; i < 4; ++i)
#pragma unroll
          for (int j = 0; j < 2; ++j)
            acc[qi * 4 + i][qj * 2 + j] = __builtin_amdgcn_mfma_f32_16x16x32_bf16(
                af[kk][i], bfr[kk][j], acc[qi * 4 + i][qj * 2 + j], 0, 0, 0);
      __builtin_amdgcn_s_setprio(0);
      __builtin_amdgcn_s_barrier();
    }
  }
}

// ---------------- gate GEMM: geg(B,S,F) bf16 = gelu(w0b @ xt^T) ----------------
__launch_bounds__(512, 2)
__global__ void gemm_gate(const unsigned short* __restrict__ w0b,
                          const unsigned short* __restrict__ xt,
                          unsigned short* __restrict__ geg) {
  __shared__ __align__(16) unsigned short sh[65536];  // 128 KiB
  const int tid = threadIdx.x;
  const int bz = blockIdx.z;
  int lin = blockIdx.y * 8 + blockIdx.x;          // gridDim = (8 s-tiles, 64 f-tiles)
  int swz = (lin & 7) * 64 + (lin >> 3);          // XCD k owns s-tile k (B-panel L2-resident)
  const int f0 = (swz & 63) * 256;
  const int s0 = (swz >> 6) * 256;
  const unsigned short* ag = w0b + (size_t)f0 * D_;
  const unsigned short* bg = xt + (size_t)bz * S_ * D_ + (size_t)s0 * D_;
  f32x4 acc[8][4] = {};
  mainloop_256(ag, bg, D_, D_ / 64, sh, tid, acc);

  const int lane = tid & 63, wid = tid >> 6;
  const int wm = (wid >> 2) * 128, wn = (wid & 3) * 64;
  const int lr = lane & 15, kq = lane >> 4;
  unsigned short* gb = geg + (size_t)bz * S_ * F_ + (size_t)s0 * F_ + f0;
#pragma unroll
  for (int i = 0; i < 8; ++i)
#pragma unroll
    for (int j = 0; j < 4; ++j) {
      const int f = wm + i * 16 + kq * 4;          // 4 consecutive f per lane
      const int s = wn + j * 16 + lr;
      u16x4 o;
#pragma unroll
      for (int r = 0; r < 4; ++r) {
        float g = acc[i][j][r];
        o[r] = f2bf(0.5f * g * (1.0f + erff(g * 0.70710678118654752f)));
      }
      *(u16x4*)(gb + (size_t)s * F_ + f) = o;
    }
}

// ---------------- up GEMM + fuse: ht(B,S,F) bf16 = geg * (w1b @ xt^T) ----------------
__launch_bounds__(512, 2)
__global__ void gemm_up(const unsigned short* __restrict__ w1b,
                        const unsigned short* __restrict__ xt,
                        const unsigned short* __restrict__ geg,
                        unsigned short* __restrict__ ht) {
  __shared__ __align__(16) unsigned short sh[65536];
  const int tid = threadIdx.x;
  const int bz = blockIdx.z;
  int lin = blockIdx.y * 8 + blockIdx.x;
  int swz = (lin & 7) * 64 + (lin >> 3);
  const int f0 = (swz & 63) * 256;
  const int s0 = (swz >> 6) * 256;
  const unsigned short* ag = w1b + (size_t)f0 * D_;
  const unsigned short* bg = xt + (size_t)bz * S_ * D_ + (size_t)s0 * D_;
  f32x4 acc[8][4] = {};
  mainloop_256(ag, bg, D_, D_ / 64, sh, tid, acc);

  const int lane = tid & 63, wid = tid >> 6;
  const int wm = (wid >> 2) * 128, wn = (wid & 3) * 64;
  const int lr = lane & 15, kq = lane >> 4;
  const unsigned short* gb = geg + (size_t)bz * S_ * F_ + (size_t)s0 * F_ + f0;
  unsigned short* hb = ht + (size_t)bz * S_ * F_ + (size_t)s0 * F_ + f0;
#pragma unroll
  for (int i = 0; i < 8; ++i)
#pragma unroll
    for (int j = 0; j < 4; ++j) {
      const int f = wm + i * 16 + kq * 4;
      const int s = wn + j * 16 + lr;
      u16x4 gv = *(const u16x4*)(gb + (size_t)s * F_ + f);
      u16x4 o;
#pragma unroll
      for (int r = 0; r < 4; ++r)
        o[r] = f2bf(bf2f(gv[r]) * acc[i][j][r]);
      *(u16x4*)(hb + (size_t)s * F_ + f) = o;
    }
}

// ---------------- GEMM2: out(B,D,S) f32 = w_out(D,F) @ ht(B,S,F)^T ----------------
__launch_bounds__(512, 2)
__global__ void gemm_out(const unsigned short* __restrict__ woutb,
                         const unsigned short* __restrict__ ht,
                         float* __restrict__ out) {
  __shared__ __align__(16) unsigned short sh[65536];
  const int tid = threadIdx.x;
  const int bz = blockIdx.z;
  int lin = blockIdx.y * 8 + blockIdx.x;          // gridDim = (8 s-tiles, 16 d-tiles)
  int swz = (lin & 7) * 16 + (lin >> 3);
  const int d0 = (swz & 15) * 256;
  const int s0 = (swz >> 4) * 256;
  const unsigned short* ag = woutb + (size_t)d0 * F_;
  const unsigned short* bg = ht + (size_t)bz * S_ * F_ + (size_t)s0 * F_;
  f32x4 acc[8][4] = {};
  mainloop_256(ag, bg, F_, F_ / 64, sh, tid, acc);

  const int lane = tid & 63, wid = tid >> 6;
  const int wm = (wid >> 2) * 128, wn = (wid & 3) * 64;
  const int lr = lane & 15, kq = lane >> 4;
  float* outb = out + (size_t)bz * D_ * S_;
#pragma unroll
  for (int i = 0; i < 8; ++i)
#pragma unroll
    for (int j = 0; j < 4; ++j) {
      const int n = wn + j * 16 + lr;
#pragma unroll
      for (int r = 0; r < 4; ++r) {
        const int m = wm + i * 16 + kq * 4 + r;
        outb[(size_t)(d0 + m) * S_ + s0 + n] = acc[i][j][r];
      }
    }
}

// ---------------- launch ----------------
extern "C" void kernel_launch(void* const* d_in, const int* in_sizes, int n_in,
                              void* d_out, int out_size, void* d_ws, size_t ws_size,
                              hipStream_t stream) {
  const float* x     = (const float*)d_in[0];
  const float* w0    = (const float*)d_in[1];
  const float* w1    = (const float*)d_in[2];
  const float* w_out = (const float*)d_in[3];
  float* out = (float*)d_out;

  char* ws = (char*)d_ws;
  // layout (bytes): w0b 128M | w1b 128M | xt 32M | ht 128M | geg/woutb 128M = 544 MiB
  unsigned short* w0b   = (unsigned short*)(ws);
  unsigned short* w1b   = (unsigned short*)(ws + 134217728UL);
  unsigned short* xt    = (unsigned short*)(ws + 268435456UL);
  unsigned short* ht    = (unsigned short*)(ws + 301989888UL);
  unsigned short* geg   = (unsigned short*)(ws + 436207616UL);  // reused as woutb later
  unsigned short* woutb = geg;

  const int n4 = (F_ * D_) / 4;  // 16,777,216 float4 per weight matrix
  hipLaunchKernelGGL(cvt_kernel, dim3(n4 / 256), dim3(256), 0, stream,
                     (const float4*)w0, (ushort4*)w0b, n4);
  hipLaunchKernelGGL(cvt_kernel, dim3(n4 / 256), dim3(256), 0, stream,
                     (const float4*)w1, (ushort4*)w1b, n4);
  hipLaunchKernelGGL(transpose_cast_kernel, dim3(S_ / 32, D_ / 32, B_), dim3(32, 8), 0, stream,
                     x, xt);
  hipLaunchKernelGGL(gemm_gate, dim3(8, F_ / 256, B_), dim3(512), 0, stream,
                     w0b, xt, geg);
  hipLaunchKernelGGL(gemm_up, dim3(8, F_ / 256, B_), dim3(512), 0, stream,
                     w1b, xt, geg, ht);
  // convert w_out AFTER gemm_up so woutb can overlap geg's storage
  hipLaunchKernelGGL(cvt_kernel, dim3(n4 / 256), dim3(256), 0, stream,
                     (const float4*)w_out, (ushort4*)woutb, n4);
  hipLaunchKernelGGL(gemm_out, dim3(8, D_ / 256, B_), dim3(512), 0, stream,
                     woutb, ht, out);
}